// Round 5
// baseline (1080.594 us; speedup 1.0000x reference)
//
#include <hip/hip_runtime.h>

typedef _Float16 f16;
typedef _Float16 f16x8 __attribute__((ext_vector_type(8)));
typedef float f32x16 __attribute__((ext_vector_type(16)));

#define MFMA32(A, B, C) __builtin_amdgcn_mfma_f32_32x32x16_f16(A, B, C, 0, 0, 0)

constexpr int Bb = 4, Hh = 8, Ll = 2048, Dk = 64, Dm = 512, BH = 32;
constexpr int LP = 2052;                         // padded time rows for STp

constexpr size_t NW  = (size_t)512 * 2048;       // W row-major [o][k], per (tensor,hilo)
constexpr size_t NST = (size_t)Bb * LP * 512;    // STp [b][j][c], per (tensor,hilo)
constexpr size_t NFF = (size_t)BH * 64 * 4 * 64 * 8;   // Qc/Kc frag: [bh][lb64][d16:4][lane][8]
constexpr size_t NVF = (size_t)BH * 2 * 128 * 64 * 8;  // V frag: [bh][db2][l16:128][lane][8]

constexpr size_t OFF_W  = 256;
constexpr size_t OFF_ST = OFF_W + 4 * NW * sizeof(f16);
constexpr size_t OFF_FF = OFF_ST + 4 * NST * sizeof(f16);
constexpr size_t OFF_VF = OFF_FF + 4 * NFF * sizeof(f16);

// scores computed in base-2: fold log2(e)/sqrt(64) into Qc (exact softmax identity)
#define QSCALE 0.1803368801111204f

// async global->LDS, 16B per lane; LDS dest = wave-uniform base + lane*16
__device__ __forceinline__ void gload_lds16(const void* g, void* l) {
    __builtin_amdgcn_global_load_lds((const __attribute__((address_space(1))) unsigned int*)g,
                                     (__attribute__((address_space(3))) unsigned int*)l, 16, 0, 0);
}

// ---------------- P1: mask + split conv weights, row-major W[o][k=f*512+c] hi/lo ----------------
__global__ void kprep_w(const float* __restrict__ convq, const float* __restrict__ convk,
                        const float* __restrict__ w, int* __restrict__ flag,
                        f16* __restrict__ wqh, f16* __restrict__ wql,
                        f16* __restrict__ wkh, f16* __restrict__ wkl) {
    const int len = (4.f * w[1] > 2.f * w[0]) ? 4 : 2;   // argmax([2w0,4w1]) -> FILTER_LENGTHS[ind]
    if (blockIdx.x == 0 && blockIdx.y == 0 && threadIdx.x == 0) *flag = len;
    int tid = blockIdx.x * 256 + threadIdx.x;            // 0..262143 = o*512+c
    int o = tid >> 9, c = tid & 511;
    const float* conv = blockIdx.y ? convk : convq;
    f16* dh = blockIdx.y ? wkh : wqh;
    f16* dl = blockIdx.y ? wkl : wql;
    const float4 v = *(const float4*)(conv + ((size_t)c * 512 + o) * 4);  // conv[c][o][0..3]
    float vv[4] = {v.x, v.y, v.z, v.w};
#pragma unroll
    for (int f = 0; f < 4; ++f) {
        float x = (f < len) ? vv[f] : 0.f;
        f16 hi = (f16)x;
        f16 lo = (f16)(x - (float)hi);
        size_t idx = (size_t)o * 2048 + (f << 9) + c;    // lanes: c consecutive -> coalesced
        dh[idx] = hi; dl[idx] = lo;
    }
}

// ---------------- P2: transpose + split S into STp[b][j][c] hi/lo (j = t+f, pad 2) ----------------
__global__ void kprep_s(const float* __restrict__ Q, const float* __restrict__ K,
                        f16* __restrict__ stqh, f16* __restrict__ stql,
                        f16* __restrict__ stkh, f16* __restrict__ stkl) {
    __shared__ float tile[64][65];
    int z = blockIdx.z;                 // tensor*4 + b
    int tensor = z >> 2, b = z & 3;
    const float* src = (tensor ? K : Q) + (size_t)b * Dm * Ll;
    f16* dh = (tensor ? stkh : stqh) + (size_t)b * LP * Dm;
    f16* dl = (tensor ? stkl : stql) + (size_t)b * LP * Dm;
    int j0 = blockIdx.x * 64, c0 = blockIdx.y * 64;
    int tl = threadIdx.x & 63, tg = threadIdx.x >> 6;
#pragma unroll
    for (int r = 0; r < 16; ++r) {
        int cl = (r << 2) + tg;
        int tabs = j0 + tl - 2;                          // STp[j] = S[:, j-2], zero-padded
        float v = (tabs >= 0 && tabs < Ll) ? src[(size_t)(c0 + cl) * Ll + tabs] : 0.f;
        tile[cl][tl] = v;
    }
    __syncthreads();
#pragma unroll
    for (int r = 0; r < 16; ++r) {
        int jl = (r << 2) + tg;
        int j = j0 + jl;
        if (j < LP) {
            float v = tile[tl][jl];
            f16 hi = (f16)v;
            f16 lo = (f16)(v - (float)hi);
            dh[(size_t)j * Dm + c0 + tl] = hi;
            dl[(size_t)j * Dm + c0 + tl] = lo;
        }
    }
}

// ---------------- P3: V -> frag order for PV B-operand ----------------
__global__ void kprep_v(const float* __restrict__ V, f16* __restrict__ vf) {
    int bh = blockIdx.y, l0 = blockIdx.x * 128;
    int tid = threadIdx.x;
    const float* src = V + (size_t)bh * Ll * Dk;
#pragma unroll
    for (int s = 0; s < 4; ++s) {
        int g = s * 4 + (tid >> 6);
        int lane = tid & 63;
        int l16s = g >> 1, db = g & 1;
        int khalf = lane >> 5, lane31 = lane & 31;
        int d = db * 32 + lane31;
        f16x8 out;
#pragma unroll
        for (int j = 0; j < 8; ++j) {
            int l = l0 + l16s * 16 + khalf * 8 + j;
            out[j] = (f16)src[(size_t)l * Dk + d];
        }
        size_t idx = ((((size_t)bh * 2 + db) * 128 + (l0 >> 4) + l16s) * 64 + lane) * 8;
        *(f16x8*)(vf + idx) = out;
    }
}

// ---------------- C: conv GEMM as ONE plain f16 GEMM (K'=3K concat), m97 LDS structure ----------------
// C[t][o] = sum_{k'} A'[t][k'] B'[k'][o];  slabs p=0: Ahi*Whi, p=1: Ahi*Wlo, p=2: Alo*Whi
// A[t][k=f*512+c] = STp[t+f][c] (row-major slab stage); W stored [o][k] row-major.
__global__ __launch_bounds__(256, 2) void kconv(
    const float* __restrict__ Q, const float* __restrict__ K, const int* __restrict__ flag,
    const f16* __restrict__ stqh, const f16* __restrict__ stql,
    const f16* __restrict__ stkh, const f16* __restrict__ stkl,
    const f16* __restrict__ wqh, const f16* __restrict__ wql,
    const f16* __restrict__ wkh, const f16* __restrict__ wkl,
    f16* __restrict__ ffhq, f16* __restrict__ fflq,
    f16* __restrict__ ffhk, f16* __restrict__ fflk) {
    __shared__ f16 At[128 * 64], Bt[128 * 64];   // 32 KB
    int id = blockIdx.x;                          // id&7 = oTile + 4*tensor -> XCD-pinned W reuse
    int oTile = id & 3, tensor = (id >> 2) & 1;
    int tt = (id >> 3) & 15, b = (id >> 7) & 3;
    int tid = threadIdx.x;
    int wave = tid >> 6, lane = tid & 63;
    int wm = wave >> 1, wn = wave & 1;
    int lane31 = lane & 31, khalf = lane >> 5;
    int t0 = tt * 128, o0 = oTile * 128;
    const f16* sh = (tensor ? stkh : stqh) + (size_t)b * LP * Dm;
    const f16* sl = (tensor ? stkl : stql) + (size_t)b * LP * Dm;
    const f16* wh = tensor ? wkh : wqh;
    const f16* wl = tensor ? wkl : wql;
    const float* src = (tensor ? K : Q) + (size_t)b * Hh * Ll * Dk;
    f16* dh = (tensor ? ffhk : ffhq);
    f16* dl = (tensor ? fflk : fflq);
    const float scale = tensor ? 1.f : QSCALE;
    const int klen = (*flag) << 9;                // 1024 or 2048
    const int iters = (3 * klen) >> 6;            // 48 or 96

    f32x16 acc[2][2];
#pragma unroll
    for (int i = 0; i < 2; ++i)
#pragma unroll
        for (int j = 0; j < 2; ++j)
#pragma unroll
            for (int r = 0; r < 16; ++r) acc[i][j][r] = 0.f;

    for (int it = 0; it < iters; ++it) {
        int kp = it << 6;
        int p = (kp >= 2 * klen) ? 2 : (kp >= klen ? 1 : 0);
        int k0 = kp - p * klen;                   // within [0,klen), 64-aligned
        int f = k0 >> 9, c0 = k0 & 511;
        const f16* srcA = (p == 2) ? sl : sh;
        const f16* srcB = (p == 1) ? wl : wh;
        __syncthreads();
#pragma unroll
        for (int c = 0; c < 4; ++c) {
            int s = c * 256 + tid;                // LDS chunk slot (16B units)
            int row = s >> 3;
            int gk = ((s & 7) ^ (row & 7)) * 8;   // XOR swizzle on global column
            gload_lds16(srcA + (size_t)(t0 + f + row) * 512 + c0 + gk, &At[s * 8]);
            gload_lds16(srcB + (size_t)(o0 + row) * 2048 + k0 + gk, &Bt[s * 8]);
        }
        __syncthreads();
#pragma unroll
        for (int kk = 0; kk < 4; ++kk) {
            int cc = (kk << 1) + khalf;           // global 16B chunk column
            f16x8 av[2], bv[2];
#pragma unroll
            for (int i = 0; i < 2; ++i) {
                int row = wm * 64 + i * 32 + lane31;
                av[i] = *(const f16x8*)&At[(row * 8 + (cc ^ (row & 7))) * 8];
            }
#pragma unroll
            for (int j = 0; j < 2; ++j) {
                int row = wn * 64 + j * 32 + lane31;
                bv[j] = *(const f16x8*)&Bt[(row * 8 + (cc ^ (row & 7))) * 8];
            }
#pragma unroll
            for (int i = 0; i < 2; ++i)
#pragma unroll
                for (int j = 0; j < 2; ++j)
                    acc[i][j] = MFMA32(av[i], bv[j], acc[i][j]);
        }
    }
    // epilogue: C[t][o] -> flat (h,l,d), add residual, scale, split, store in kattn frag order
#pragma unroll
    for (int i = 0; i < 2; ++i)
#pragma unroll
        for (int j = 0; j < 2; ++j)
#pragma unroll
            for (int r = 0; r < 16; ++r) {
                int trow = t0 + wm * 64 + i * 32 + (r & 3) + ((r >> 2) << 3) + (khalf << 2);
                int ocol = o0 + wn * 64 + j * 32 + lane31;
                int h = trow >> 8;
                int l = ((trow & 255) << 3) + (ocol >> 6);
                int d = ocol & 63;
                float v2 = (acc[i][j][r] + src[((size_t)h * Ll + l) * Dk + d]) * scale;
                f16 hi = (f16)v2;
                f16 lo = (f16)(v2 - (float)hi);
                size_t idx = ((((size_t)(b * 8 + h) * 64 + (l >> 5)) * 4 + (d >> 4)) * 64
                              + ((d >> 3) & 1) * 32 + (l & 31)) * 8 + (d & 7);
                dh[idx] = hi; dl[idx] = lo;
            }
}

// ---------------- F: fused attention, K-split across wave pairs ----------------
__global__ __launch_bounds__(256, 4) void kattn(
    const f16* __restrict__ qfh, const f16* __restrict__ qfl,
    const f16* __restrict__ kfh, const f16* __restrict__ kfl,
    const f16* __restrict__ vf,
    float* __restrict__ ctx_out, float* __restrict__ attn_out) {
    __shared__ __align__(16) char smem[16384];       // union: combuf (16 KB) / ptile (10 KB)
    float (*combuf)[32][64] = (float (*)[32][64])smem;
    f16 (*ptile)[32][40] = (f16 (*)[32][40])smem;
    int id = blockIdx.x;                             // 1024; 4 bh per XCD for K/V L2 locality
    int bh = (id & 7) * 4 + (id >> 8);
    int qt = (id >> 3) & 31;
    int wave = threadIdx.x >> 6, lane = threadIdx.x & 63;
    int qg = wave >> 1, kg = wave & 1;
    int lane31 = lane & 31, khalf = lane >> 5;
    int q0 = qt * 64 + qg * 32;

    // resident Q fragments (hi/lo): 4 ksteps of 16 over d_k=64, contiguous 1KB loads
    f16x8 a_h[4], a_l[4];
    {
        size_t qb = ((size_t)bh * 64 + qt * 2 + qg) * 4;
#pragma unroll
        for (int ks = 0; ks < 4; ++ks) {
            a_h[ks] = *(const f16x8*)(qfh + ((qb + ks) * 64 + lane) * 8);
            a_l[ks] = *(const f16x8*)(qfl + ((qb + ks) * 64 + lane) * 8);
        }
    }
    const f16* kbh = kfh + (size_t)bh * 131072;
    const f16* kbl = kfl + (size_t)bh * 131072;
    const int ch0 = kg * 32, ch1 = ch0 + 32;

    float m[16], s[16];
#pragma unroll
    for (int r = 0; r < 16; ++r) { m[r] = -3.0e38f; s[r] = 0.f; }

    // ---- pass 1: online row max + sum of 2^z over this wave's half of K ----
#pragma unroll 2
    for (int ch = ch0; ch < ch1; ++ch) {
        f32x16 acc;
#pragma unroll
        for (int r = 0; r < 16; ++r) acc[r] = 0.f;
        size_t kb = (size_t)ch * 2048 + lane * 8;
#pragma unroll
        for (int ks = 0; ks < 4; ++ks) {
            f16x8 kh8 = *(const f16x8*)(kbh + kb + ks * 512);
            f16x8 kl8 = *(const f16x8*)(kbl + kb + ks * 512);
            acc = MFMA32(a_h[ks], kh8, acc);
            acc = MFMA32(a_h[ks], kl8, acc);
            acc = MFMA32(a_l[ks], kh8, acc);
        }
#pragma unroll
        for (int r = 0; r < 16; ++r) {
            float v = acc[r];
            float d = v - m[r];
            float e = exp2f(-fabsf(d));
            bool gt = d > 0.f;
            s[r] = gt ? __fmaf_rn(s[r], e, 1.f) : (s[r] + e);
            m[r] = gt ? v : m[r];
        }
    }
    // lane combine within the 32 col-lanes of each half
#pragma unroll
    for (int r = 0; r < 16; ++r) {
        float mm = m[r], ss = s[r];
#pragma unroll
        for (int off = 1; off < 32; off <<= 1) {
            float mo = __shfl_xor(mm, off, 64);
            float so = __shfl_xor(ss, off, 64);
            float mn = fmaxf(mm, mo);
            ss = ss * exp2f(mm - mn) + so * exp2f(mo - mn);
            mm = mn;
        }
        m[r] = mm; s[r] = ss;
    }
    // cross-wave (k-split) combine through LDS
    if (kg == 1) {
#pragma unroll
        for (int r = 0; r < 16; ++r) {
            combuf[qg][r][lane] = m[r];
            combuf[qg][16 + r][lane] = s[r];
        }
    }
    __syncthreads();
    if (kg == 0) {
#pragma unroll
        for (int r = 0; r < 16; ++r) {
            float m1 = combuf[qg][r][lane];
            float s1 = combuf[qg][16 + r][lane];
            float mn = fmaxf(m[r], m1);
            float ss = s[r] * exp2f(m[r] - mn) + s1 * exp2f(m1 - mn);
            m[r] = mn; s[r] = 1.f / ss;
            combuf[qg][r][lane] = mn;
            combuf[qg][16 + r][lane] = s[r];
        }
    }
    __syncthreads();
    if (kg == 1) {
#pragma unroll
        for (int r = 0; r < 16; ++r) {
            m[r] = combuf[qg][r][lane];
            s[r] = combuf[qg][16 + r][lane];
        }
    }
    __syncthreads();   // combuf -> ptile region handoff

    f32x16 ctx[2];
#pragma unroll
    for (int n = 0; n < 2; ++n)
#pragma unroll
        for (int r = 0; r < 16; ++r) ctx[n][r] = 0.f;

    const size_t base_q = ((size_t)bh * Ll + q0) * Ll + lane31;

    // ---- pass 2: recompute scores (identical op order), write attn (f32 direct), PV ----
    for (int ch = ch0; ch < ch1; ++ch) {
        f32x16 acc;
#pragma unroll
        for (int r = 0; r < 16; ++r) acc[r] = 0.f;
        size_t kb = (size_t)ch * 2048 + lane * 8;
#pragma unroll
        for (int ks = 0; ks < 4; ++ks) {
            f16x8 kh8 = *(const f16x8*)(kbh + kb + ks * 512);
            f16x8 kl8 = *(const f16x8*)(kbl + kb + ks * 512);
            acc = MFMA32(a_h[ks], kh8, acc);
            acc = MFMA32(a_h[ks], kl8, acc);
            acc = MFMA32(a_l[ks], kh8, acc);
        }
#pragma unroll
        for (int r = 0; r < 16; ++r) {
            float p = exp2f(acc[r] - m[r]) * s[r];
            int row = (r & 3) + ((r >> 2) << 3) + (khalf << 2);
            attn_out[base_q + (size_t)row * Ll + ch * 32] = p;   // decoupled f32 store
            ptile[wave][row][lane31] = (f16)p;
        }
        __asm__ volatile("s_waitcnt lgkmcnt(0)" ::: "memory");   // wave-private LDS RAW
#pragma unroll
        for (int ks2 = 0; ks2 < 2; ++ks2) {
            f16x8 pa = *(const f16x8*)&ptile[wave][lane31][ks2 * 16 + khalf * 8];
#pragma unroll
            for (int n = 0; n < 2; ++n) {
                size_t off = ((((size_t)bh * 2 + n) * 128 + ch * 2 + ks2) * 64 + lane) * 8;
                f16x8 vb = *(const f16x8*)(vf + off);
                ctx[n] = MFMA32(pa, vb, ctx[n]);
            }
        }
    }
    // ---- k-split ctx reduction (reuses smem as combuf after barrier) ----
    __syncthreads();
    if (kg == 1) {
#pragma unroll
        for (int n = 0; n < 2; ++n)
#pragma unroll
            for (int r = 0; r < 16; ++r) combuf[qg][n * 16 + r][lane] = ctx[n][r];
    }
    __syncthreads();
    if (kg == 0) {
#pragma unroll
        for (int n = 0; n < 2; ++n)
#pragma unroll
            for (int r = 0; r < 16; ++r) {
                float v = ctx[n][r] + combuf[qg][n * 16 + r][lane];
                int row = (r & 3) + ((r >> 2) << 3) + (khalf << 2);
                ctx_out[((size_t)bh * Ll + q0 + row) * Dk + n * 32 + lane31] = v;
            }
    }
}

extern "C" void kernel_launch(void* const* d_in, const int* in_sizes, int n_in,
                              void* d_out, int out_size, void* d_ws, size_t ws_size,
                              hipStream_t stream) {
    const float* Q = (const float*)d_in[0];
    const float* K = (const float*)d_in[1];
    const float* V = (const float*)d_in[2];
    // d_in[3] = attn_mask (all-false, unused)
    const float* convq = (const float*)d_in[4];
    const float* convk = (const float*)d_in[5];
    const float* w = (const float*)d_in[6];

    char* ws = (char*)d_ws;
    int* flag = (int*)ws;
    f16* wqh = (f16*)(ws + OFF_W);
    f16* wql = wqh + NW;
    f16* wkh = wql + NW;
    f16* wkl = wkh + NW;
    f16* stqh = (f16*)(ws + OFF_ST);
    f16* stql = stqh + NST;
    f16* stkh = stql + NST;
    f16* stkl = stkh + NST;
    f16* ffhq = (f16*)(ws + OFF_FF);
    f16* fflq = ffhq + NFF;
    f16* ffhk = fflq + NFF;
    f16* fflk = ffhk + NFF;
    f16* vf = (f16*)(ws + OFF_VF);

    float* ctx_out = (float*)d_out;
    float* attn_out = ctx_out + (size_t)BH * Ll * Dk;

    kprep_w<<<dim3(1024, 2), 256, 0, stream>>>(convq, convk, w, flag, wqh, wql, wkh, wkl);
    kprep_s<<<dim3(33, 8, 8), 256, 0, stream>>>(Q, K, stqh, stql, stkh, stkl);
    kprep_v<<<dim3(16, 32), 256, 0, stream>>>(V, vf);
    kconv<<<dim3(512), 256, 0, stream>>>(Q, K, flag, stqh, stql, stkh, stkl,
                                         wqh, wql, wkh, wkl, ffhq, fflq, ffhk, fflk);
    kattn<<<dim3(1024), 256, 0, stream>>>(ffhq, fflq, ffhk, fflk, vf, ctx_out, attn_out);
}